// Round 1
// baseline (679.436 us; speedup 1.0000x reference)
//
#include <hip/hip_runtime.h>

typedef __attribute__((ext_vector_type(8))) short short8;
typedef __attribute__((ext_vector_type(4))) short short4_;
typedef __attribute__((ext_vector_type(4))) float f32x4;

#define MFMA16(a, b, c) __builtin_amdgcn_mfma_f32_16x16x32_bf16(a, b, c, 0, 0, 0)

__device__ __forceinline__ short f2bf(float f) {
  unsigned u = __float_as_uint(f);
  unsigned r = (u + 0x7FFFu + ((u >> 16) & 1u)) >> 16;  // RNE
  return (short)r;
}

// swizzled score index: rotate within 32-word blocks by 4*(m&7) to avoid
// 16-way bank conflicts on PV A-fragment reads (stride 1024 words otherwise)
__device__ __forceinline__ int sidx(int m, int j) {
  return (m << 10) + (j & ~31) + ((j + ((m & 7) << 2)) & 31);
}

// ---------------- converts ----------------

__global__ void cvt_f32_bf16(const float* __restrict__ src, short* __restrict__ dst, int n4) {
  int i = blockIdx.x * 256 + threadIdx.x;
  if (i >= n4) return;
  f32x4 v = ((const f32x4*)src)[i];
  short4_ o;
  o[0] = f2bf(v[0]); o[1] = f2bf(v[1]); o[2] = f2bf(v[2]); o[3] = f2bf(v[3]);
  ((short4_*)dst)[i] = o;
}

// pos_encoding: 16376 real rows of 512, pad to 16384 rows with zeros
__global__ void cvt_pos(const float* __restrict__ src, short* __restrict__ dst, int n4) {
  int i = blockIdx.x * 256 + threadIdx.x;
  if (i >= n4) return;
  int m = (i * 4) >> 9;
  short4_ o;
  if (m < 16376) {
    f32x4 v = ((const f32x4*)src)[i];
    o[0] = f2bf(v[0]); o[1] = f2bf(v[1]); o[2] = f2bf(v[2]); o[3] = f2bf(v[3]);
  } else {
    o[0] = 0; o[1] = 0; o[2] = 0; o[3] = 0;
  }
  ((short4_*)dst)[i] = o;
}

// Wt[n][k] = bf16(W[k][n])   (512x512)
__global__ void cvt_wt(const float* __restrict__ W, short* __restrict__ Wt) {
  int id = blockIdx.x * 256 + threadIdx.x;
  int n = id & 511, k = id >> 9;
  Wt[n * 512 + k] = f2bf(W[k * 512 + n]);
}

// ---------------- projection GEMM ----------------
// C[m][n] = sum_k A[m][k] * Bt[n][k], tile 64x64, K=512, 4 waves
// MODE 0: q -> qu,qv (+bias, *0.125) [B,H,S,Dh]
// MODE 1: k -> [B,H,S,Dh]
// MODE 2: v -> [B,H,Dh,S] (LDS transpose)
// MODE 3: p -> [B,H,2048,Dh], rows m=b*2047+r, skip m>=16376
// MODE 4: out fp32 [8192][512]
template <int MODE>
__global__ __launch_bounds__(256) void proj_gemm(
    const short* __restrict__ A, const short* __restrict__ Bt,
    const float* __restrict__ biasU, const float* __restrict__ biasV,
    short* __restrict__ o1, short* __restrict__ o2, float* __restrict__ o3) {
  const int tid = threadIdx.x;
  const int w = tid >> 6, l = tid & 63, q = l >> 4, c = l & 15;
  const int m0 = blockIdx.x * 64, n0 = blockIdx.y * 64;

  const short* ap = A + (m0 + w * 16 + c) * 512 + q * 8;
  const short* bp = Bt + (n0 + c) * 512 + q * 8;

  f32x4 acc[4] = {};
#pragma unroll
  for (int kk = 0; kk < 512; kk += 32) {
    short8 a = *(const short8*)(ap + kk);
#pragma unroll
    for (int nn = 0; nn < 4; nn++) {
      short8 b = *(const short8*)(bp + nn * 16 * 512 + kk);
      acc[nn] = MFMA16(a, b, acc[nn]);
    }
  }

  __shared__ short vtile[64][72];

#pragma unroll
  for (int nn = 0; nn < 4; nn++) {
#pragma unroll
    for (int r = 0; r < 4; r++) {
      int m = m0 + w * 16 + q * 4 + r;
      int n = n0 + nn * 16 + c;
      float v = acc[nn][r];
      if (MODE == 0) {
        int b = m >> 10, s = m & 1023, h = n >> 6, d = n & 63;
        int idx = (((b * 8 + h) * 1024 + s) << 6) + d;
        o1[idx] = f2bf((v + biasU[n]) * 0.125f);
        o2[idx] = f2bf((v + biasV[n]) * 0.125f);
      } else if (MODE == 1) {
        int b = m >> 10, s = m & 1023, h = n >> 6, d = n & 63;
        o1[(((b * 8 + h) * 1024 + s) << 6) + d] = f2bf(v);
      } else if (MODE == 2) {
        vtile[w * 16 + q * 4 + r][nn * 16 + c] = f2bf(v);
      } else if (MODE == 3) {
        if (m < 16376) {
          int b = m / 2047, rr = m - b * 2047;
          int h = n >> 6, d = n & 63;
          o1[(((b * 8 + h) * 2048 + rr) << 6) + d] = f2bf(v);
        }
      } else {
        o3[m * 512 + n] = v;
      }
    }
  }

  if (MODE == 2) {
    __syncthreads();
    int b = m0 >> 10, h = n0 >> 6, s0 = m0 & 1023;
#pragma unroll
    for (int it = 0; it < 2; it++) {
      int id = tid + it * 256;  // 0..511
      int d = id >> 3, ch = id & 7;
      short8 pk;
#pragma unroll
      for (int jj = 0; jj < 8; jj++) pk[jj] = vtile[ch * 8 + jj][d];
      *(short8*)(o1 + (((b * 8 + h) * 64 + d) << 10) + s0 + ch * 8) = pk;
    }
  }
}

// ---------------- fused attention ----------------
// one WG per (b, h, 16 q-rows). Full score row [16][1024] fp32 in 64KB LDS.
__global__ __launch_bounds__(256) void attn_kernel(
    const short* __restrict__ qu, const short* __restrict__ qv,
    const short* __restrict__ kb, const short* __restrict__ vT,
    const short* __restrict__ pb, short* __restrict__ ctx) {
  __shared__ float sc[16 * 1024];

  const int tid = threadIdx.x;
  const int w = tid >> 6, l = tid & 63, q = l >> 4, c = l & 15;
  const int it64 = blockIdx.x & 63;
  const int h = (blockIdx.x >> 6) & 7;
  const int b = blockIdx.x >> 9;
  const int i0 = it64 << 4;
  const int bh = b * 8 + h;

  // Phase 1: content scores  sc[m][j] = qu[i0+m] . k[j]
  {
    const short* qp = qu + ((bh * 1024 + i0 + c) << 6) + q * 8;
    short8 a0 = *(const short8*)(qp);
    short8 a1 = *(const short8*)(qp + 32);
    for (int t = 0; t < 16; t++) {
      int j0 = (t * 4 + w) << 4;
      const short* kp = kb + ((bh * 1024 + j0 + c) << 6) + q * 8;
      short8 b0 = *(const short8*)(kp);
      short8 b1 = *(const short8*)(kp + 32);
      f32x4 cc = {0.f, 0.f, 0.f, 0.f};
      cc = MFMA16(a0, b0, cc);
      cc = MFMA16(a1, b1, cc);
#pragma unroll
      for (int r = 0; r < 4; r++) {
        int m = q * 4 + r;
        sc[sidx(m, j0 + c)] = cc[r];
      }
    }
  }
  __syncthreads();

  // Phase 2: pos band  sc[m][j] += qv[i0+m] . p[j - (i0+m) + 1023]
  {
    const short* qp = qv + ((bh * 1024 + i0 + c) << 6) + q * 8;
    short8 a0 = *(const short8*)(qp);
    short8 a1 = *(const short8*)(qp + 32);
    const int r_lo = 1008 - i0;  // covers r in [1008-i0, 2047-i0]
    for (int t = 0;; t++) {
      int rt = w + 4 * t;
      if (rt >= 65) break;
      int r0 = r_lo + (rt << 4);
      const short* pp = pb + ((bh * 2048 + r0 + c) << 6) + q * 8;
      short8 b0 = *(const short8*)(pp);
      short8 b1 = *(const short8*)(pp + 32);
      f32x4 cc = {0.f, 0.f, 0.f, 0.f};
      cc = MFMA16(a0, b0, cc);
      cc = MFMA16(a1, b1, cc);
#pragma unroll
      for (int r = 0; r < 4; r++) {
        int m = q * 4 + r;
        int j = r0 + c - 1023 + i0 + m;
        if ((unsigned)j < 1024u) sc[sidx(m, j)] += cc[r];
      }
    }
  }
  __syncthreads();

  // Phase 3: softmax per row, normalized in place (16 lanes per row, in-wave)
  {
    int row = tid >> 4, c0 = tid & 15;
    float mx = -1e30f;
    for (int j = c0; j < 1024; j += 16) mx = fmaxf(mx, sc[sidx(row, j)]);
    mx = fmaxf(mx, __shfl_xor(mx, 1));
    mx = fmaxf(mx, __shfl_xor(mx, 2));
    mx = fmaxf(mx, __shfl_xor(mx, 4));
    mx = fmaxf(mx, __shfl_xor(mx, 8));
    float sum = 0.f;
    for (int j = c0; j < 1024; j += 16) {
      int idx = sidx(row, j);
      float e = __expf(sc[idx] - mx);
      sc[idx] = e;
      sum += e;
    }
    sum += __shfl_xor(sum, 1);
    sum += __shfl_xor(sum, 2);
    sum += __shfl_xor(sum, 4);
    sum += __shfl_xor(sum, 8);
    float rs = 1.0f / sum;
    for (int j = c0; j < 1024; j += 16) sc[sidx(row, j)] *= rs;
  }
  __syncthreads();

  // Phase 4: PV — wave w computes O[0:16][w*16 : w*16+16]
  {
    f32x4 acc = {0.f, 0.f, 0.f, 0.f};
    const short* vp = vT + ((bh * 64 + w * 16 + c) << 10);
    const int m = c;  // A-frag row
    const int rot = (m & 7) << 2;
    const float* rowbase = &sc[m << 10];
    for (int jt = 0; jt < 32; jt++) {
      int j0 = jt << 5;
      short8 bv = *(const short8*)(vp + j0 + q * 8);
      f32x4 pA = *(const f32x4*)(rowbase + j0 + ((q * 8 + rot) & 31));
      f32x4 pB = *(const f32x4*)(rowbase + j0 + ((q * 8 + 4 + rot) & 31));
      short8 pa;
      pa[0] = f2bf(pA[0]); pa[1] = f2bf(pA[1]); pa[2] = f2bf(pA[2]); pa[3] = f2bf(pA[3]);
      pa[4] = f2bf(pB[0]); pa[5] = f2bf(pB[1]); pa[6] = f2bf(pB[2]); pa[7] = f2bf(pB[3]);
      acc = MFMA16(pa, bv, acc);
    }
#pragma unroll
    for (int r = 0; r < 4; r++) {
      int row = q * 4 + r;
      ctx[((b * 1024 + i0 + row) << 9) + h * 64 + w * 16 + c] = f2bf(acc[r]);
    }
  }
}

// ---------------- launcher ----------------

extern "C" void kernel_launch(void* const* d_in, const int* in_sizes, int n_in,
                              void* d_out, int out_size, void* d_ws, size_t ws_size,
                              hipStream_t stream) {
  const float* query = (const float*)d_in[0];
  const float* key   = (const float*)d_in[1];
  const float* value = (const float*)d_in[2];
  const float* pos   = (const float*)d_in[3];
  const float* Wq    = (const float*)d_in[4];
  const float* Wk    = (const float*)d_in[5];
  const float* Wv    = (const float*)d_in[6];
  const float* Wp    = (const float*)d_in[7];
  const float* ub    = (const float*)d_in[8];
  const float* vb    = (const float*)d_in[9];
  const float* Wo    = (const float*)d_in[10];

  char* p = (char*)d_ws;
  auto alloc = [&](size_t bytes) {
    char* r = p;
    p += (bytes + 255) & ~(size_t)255;
    return r;
  };
  short* Xq  = (short*)alloc(8192 * 512 * 2);
  short* Xk  = (short*)alloc(8192 * 512 * 2);
  short* Xv  = (short*)alloc(8192 * 512 * 2);
  short* Xp  = (short*)alloc((size_t)16384 * 512 * 2);
  short* WtQ = (short*)alloc(512 * 512 * 2);
  short* WtK = (short*)alloc(512 * 512 * 2);
  short* WtV = (short*)alloc(512 * 512 * 2);
  short* WtP = (short*)alloc(512 * 512 * 2);
  short* WtO = (short*)alloc(512 * 512 * 2);
  short* quB = (short*)alloc((size_t)8 * 8 * 1024 * 64 * 2);
  short* qvB = (short*)alloc((size_t)8 * 8 * 1024 * 64 * 2);
  short* kbB = (short*)alloc((size_t)8 * 8 * 1024 * 64 * 2);
  short* vTB = (short*)alloc((size_t)8 * 8 * 1024 * 64 * 2);
  short* pbB = (short*)alloc((size_t)8 * 8 * 2048 * 64 * 2);
  short* ctxB = (short*)alloc((size_t)8 * 1024 * 512 * 2);

  cvt_f32_bf16<<<4096, 256, 0, stream>>>(query, Xq, 1048576);
  cvt_f32_bf16<<<4096, 256, 0, stream>>>(key, Xk, 1048576);
  cvt_f32_bf16<<<4096, 256, 0, stream>>>(value, Xv, 1048576);
  cvt_pos<<<8192, 256, 0, stream>>>(pos, Xp, 2097152);
  cvt_wt<<<1024, 256, 0, stream>>>(Wq, WtQ);
  cvt_wt<<<1024, 256, 0, stream>>>(Wk, WtK);
  cvt_wt<<<1024, 256, 0, stream>>>(Wv, WtV);
  cvt_wt<<<1024, 256, 0, stream>>>(Wp, WtP);
  cvt_wt<<<1024, 256, 0, stream>>>(Wo, WtO);

  proj_gemm<0><<<dim3(128, 8), 256, 0, stream>>>(Xq, WtQ, ub, vb, quB, qvB, nullptr);
  proj_gemm<1><<<dim3(128, 8), 256, 0, stream>>>(Xk, WtK, nullptr, nullptr, kbB, nullptr, nullptr);
  proj_gemm<2><<<dim3(128, 8), 256, 0, stream>>>(Xv, WtV, nullptr, nullptr, vTB, nullptr, nullptr);
  proj_gemm<3><<<dim3(256, 8), 256, 0, stream>>>(Xp, WtP, nullptr, nullptr, pbB, nullptr, nullptr);

  attn_kernel<<<4096, 256, 0, stream>>>(quB, qvB, kbB, vTB, pbB, ctxB);

  proj_gemm<4><<<dim3(128, 8), 256, 0, stream>>>(ctxB, WtO, nullptr, nullptr, nullptr, nullptr,
                                                 (float*)d_out);
}

// Round 2
// 416.861 us; speedup vs baseline: 1.6299x; 1.6299x over previous
//
#include <hip/hip_runtime.h>

typedef __attribute__((ext_vector_type(8))) short short8;
typedef __attribute__((ext_vector_type(4))) short short4_;
typedef __attribute__((ext_vector_type(4))) float f32x4;

#define MFMA16(a, b, c) __builtin_amdgcn_mfma_f32_16x16x32_bf16(a, b, c, 0, 0, 0)

__device__ __forceinline__ short f2bf(float f) {
  unsigned u = __float_as_uint(f);
  unsigned r = (u + 0x7FFFu + ((u >> 16) & 1u)) >> 16;  // RNE
  return (short)r;
}

__device__ __forceinline__ void glds16(const short* g, short* l) {
  __builtin_amdgcn_global_load_lds((const __attribute__((address_space(1))) unsigned int*)g,
                                   (__attribute__((address_space(3))) unsigned int*)l, 16, 0, 0);
}

// swizzled score index: rotate within 32-word blocks by 4*(m&7)
__device__ __forceinline__ int sidx(int m, int j) {
  return (m << 10) + (j & ~31) + ((j + ((m & 7) << 2)) & 31);
}

// ---------------- converts ----------------

__global__ void cvt3(const float* __restrict__ s0, const float* __restrict__ s1,
                     const float* __restrict__ s2, short* __restrict__ d0,
                     short* __restrict__ d1, short* __restrict__ d2) {
  int i = blockIdx.x * 256 + threadIdx.x;
  const float* s = (blockIdx.y == 0) ? s0 : (blockIdx.y == 1) ? s1 : s2;
  short* d = (blockIdx.y == 0) ? d0 : (blockIdx.y == 1) ? d1 : d2;
  f32x4 v = ((const f32x4*)s)[i];
  short4_ o;
  o[0] = f2bf(v[0]); o[1] = f2bf(v[1]); o[2] = f2bf(v[2]); o[3] = f2bf(v[3]);
  ((short4_*)d)[i] = o;
}

__global__ void cvt_pos(const float* __restrict__ src, short* __restrict__ dst, int n4) {
  int i = blockIdx.x * 256 + threadIdx.x;
  if (i >= n4) return;
  int m = (i * 4) >> 9;
  short4_ o;
  if (m < 16376) {
    f32x4 v = ((const f32x4*)src)[i];
    o[0] = f2bf(v[0]); o[1] = f2bf(v[1]); o[2] = f2bf(v[2]); o[3] = f2bf(v[3]);
  } else {
    o[0] = 0; o[1] = 0; o[2] = 0; o[3] = 0;
  }
  ((short4_*)dst)[i] = o;
}

// Wt[n][k] = bf16(W[k][n])   (512x512), 5 weights in one launch
__global__ void cvt_wt5(const float* __restrict__ W0, const float* __restrict__ W1,
                        const float* __restrict__ W2, const float* __restrict__ W3,
                        const float* __restrict__ W4, short* __restrict__ T0,
                        short* __restrict__ T1, short* __restrict__ T2,
                        short* __restrict__ T3, short* __restrict__ T4) {
  int id = blockIdx.x * 256 + threadIdx.x;
  int n = id & 511, k = id >> 9;
  const float* W = (blockIdx.y == 0) ? W0 : (blockIdx.y == 1) ? W1
                 : (blockIdx.y == 2) ? W2 : (blockIdx.y == 3) ? W3 : W4;
  short* T = (blockIdx.y == 0) ? T0 : (blockIdx.y == 1) ? T1
           : (blockIdx.y == 2) ? T2 : (blockIdx.y == 3) ? T3 : T4;
  T[n * 512 + k] = f2bf(W[k * 512 + n]);
}

// ---------------- m97-style projection GEMM ----------------
// C[m][n] = sum_k A[m][k]*Bt[n][k], tile 128x128, BK=32, global_load_lds staging
// MODE 0: q -> qu,qv (+bias, *0.125) [B,H,S,Dh]
// MODE 1: k -> [B,H,S,Dh]
// MODE 2: v -> [B,H,Dh,S] (LDS transpose)
// MODE 3: p -> [B,H,2048,Dh], rows m=b*2047+r, skip m>=16376
// MODE 4: out fp32 [8192][512]
template <int MODE>
__global__ __launch_bounds__(256, 2) void proj2(
    const short* __restrict__ A, const short* __restrict__ Bt,
    const float* __restrict__ biasU, const float* __restrict__ biasV,
    short* __restrict__ o1, short* __restrict__ o2, float* __restrict__ o3) {
  __shared__ short smem[8192];  // As = [0,4096) = [128][32], Bs = [4096,8192)
  short* As = smem;
  short* Bs = smem + 4096;

  const int tid = threadIdx.x;
  const int w = tid >> 6, l = tid & 63, q = l >> 4, c = l & 15;
  const int wm = (w & 1) << 6, wn = (w >> 1) << 6;
  const int m0 = blockIdx.x * 128, n0 = blockIdx.y * 128;

  f32x4 acc[4][4] = {};

  for (int kk = 0; kk < 512; kk += 32) {
    // stage A and B tiles: 2 x 16B chunks each per thread
#pragma unroll
    for (int i = 0; i < 2; i++) {
      int ci = i * 256 + tid;  // chunk index 0..511
      glds16(A + (m0 + (ci >> 2)) * 512 + kk + ((ci & 3) << 3), As + ci * 8);
      glds16(Bt + (n0 + (ci >> 2)) * 512 + kk + ((ci & 3) << 3), Bs + ci * 8);
    }
    __syncthreads();  // drains vmcnt(0): staged data visible

    short8 af[4], bf[4];
#pragma unroll
    for (int i = 0; i < 4; i++) {
      af[i] = *(const short8*)(As + (wm + i * 16 + c) * 32 + q * 8);
      bf[i] = *(const short8*)(Bs + (wn + i * 16 + c) * 32 + q * 8);
    }
#pragma unroll
    for (int i = 0; i < 4; i++)
#pragma unroll
      for (int j = 0; j < 4; j++) acc[i][j] = MFMA16(af[i], bf[j], acc[i][j]);
    __syncthreads();  // done reading before next stage overwrites
  }

  if (MODE == 2) {
    // transpose 128x128 C (bf16) via 2 chunks of 64x128 through smem
    const int bq = m0 >> 10;
#pragma unroll
    for (int ch = 0; ch < 2; ch++) {
      __syncthreads();
      if ((w & 1) == ch) {
#pragma unroll
        for (int i = 0; i < 4; i++)
#pragma unroll
          for (int j = 0; j < 4; j++)
#pragma unroll
            for (int r = 0; r < 4; r++)
              smem[(i * 16 + q * 4 + r) * 128 + wn + j * 16 + c] = f2bf(acc[i][j][r]);
      }
      __syncthreads();
      int d = tid >> 1, s0 = (tid & 1) << 5;
      int n = n0 + d, hh = n >> 6, dd = n & 63;
      int sbase = (m0 & 1023) + ch * 64 + s0;
      short* op = o1 + (((bq * 8 + hh) * 64 + dd) << 10) + sbase;
#pragma unroll
      for (int k2 = 0; k2 < 4; k2++) {
        short8 pk;
#pragma unroll
        for (int e = 0; e < 8; e++) pk[e] = smem[(s0 + k2 * 8 + e) * 128 + d];
        *(short8*)(op + (k2 << 3)) = pk;
      }
    }
    return;
  }

#pragma unroll
  for (int i = 0; i < 4; i++)
#pragma unroll
    for (int j = 0; j < 4; j++) {
      int n = n0 + wn + j * 16 + c;
      float bu = 0.f, bv = 0.f;
      if (MODE == 0) { bu = biasU[n]; bv = biasV[n]; }
#pragma unroll
      for (int r = 0; r < 4; r++) {
        int mg = m0 + wm + i * 16 + q * 4 + r;
        float v = acc[i][j][r];
        if (MODE == 0) {
          int b = mg >> 10, s = mg & 1023, h = n >> 6, d = n & 63;
          int idx = (((b * 8 + h) * 1024 + s) << 6) + d;
          o1[idx] = f2bf((v + bu) * 0.125f);
          o2[idx] = f2bf((v + bv) * 0.125f);
        } else if (MODE == 1) {
          int b = mg >> 10, s = mg & 1023, h = n >> 6, d = n & 63;
          o1[(((b * 8 + h) * 1024 + s) << 6) + d] = f2bf(v);
        } else if (MODE == 3) {
          if (mg < 16376) {
            int b = mg / 2047, rr = mg - b * 2047;
            int h = n >> 6, d = n & 63;
            o1[(((b * 8 + h) * 2048 + rr) << 6) + d] = f2bf(v);
          }
        } else {
          o3[mg * 512 + n] = v;
        }
      }
    }
}

// ---------------- fused attention ----------------
// one WG per (b, h, 16 q-rows). bh = blk&63 -> all 64 WGs of a (b,h) on one XCD.
__global__ __launch_bounds__(256, 2) void attn_kernel(
    const short* __restrict__ qu, const short* __restrict__ qv,
    const short* __restrict__ kb, const short* __restrict__ vT,
    const short* __restrict__ pb, short* __restrict__ ctx) {
  __shared__ float sc[16 * 1024];
  __shared__ float rsArr[16];

  const int tid = threadIdx.x;
  const int w = tid >> 6, l = tid & 63, q = l >> 4, c = l & 15;
  const int bh = blockIdx.x & 63;
  const int i0 = (blockIdx.x >> 6) << 4;
  const int b = bh >> 3, h = bh & 7;

  // Phase 1: content scores  sc[m][j] = qu[i0+m] . k[j]
  {
    const short* qp = qu + ((bh << 10) + i0 + c) * 64 + q * 8;
    short8 a0 = *(const short8*)(qp);
    short8 a1 = *(const short8*)(qp + 32);
    const short* kpb = kb + ((bh << 10) + c) * 64 + q * 8;
#pragma unroll 4
    for (int t = 0; t < 16; t++) {
      int j0 = (t * 4 + w) << 4;
      const short* kp = kpb + j0 * 64;
      short8 b0 = *(const short8*)(kp);
      short8 b1 = *(const short8*)(kp + 32);
      f32x4 cc = {0.f, 0.f, 0.f, 0.f};
      cc = MFMA16(a0, b0, cc);
      cc = MFMA16(a1, b1, cc);
#pragma unroll
      for (int r = 0; r < 4; r++) sc[sidx(q * 4 + r, j0 + c)] = cc[r];
    }
  }
  __syncthreads();

  // Phase 2: pos band  sc[m][j] += qv[i0+m] . p[j-(i0+m)+1023];  j = rt*16-15+c+m
  {
    const short* qp = qv + ((bh << 10) + i0 + c) * 64 + q * 8;
    short8 a0 = *(const short8*)(qp);
    short8 a1 = *(const short8*)(qp + 32);
    const short* ppb = pb + ((bh << 11) + c) * 64 + q * 8;
    const int r_lo = 1008 - i0;
#pragma unroll 4
    for (int t = 0; t < 17; t++) {
      int rt = w + 4 * t;  // up to 67; OOB rows predicated out below
      int r0 = r_lo + (rt << 4);
      const short* pp = ppb + r0 * 64;
      short8 b0 = *(const short8*)(pp);
      short8 b1 = *(const short8*)(pp + 32);
      f32x4 cc = {0.f, 0.f, 0.f, 0.f};
      cc = MFMA16(a0, b0, cc);
      cc = MFMA16(a1, b1, cc);
#pragma unroll
      for (int r = 0; r < 4; r++) {
        int m = q * 4 + r;
        int j = rt * 16 - 15 + c + m;
        if ((unsigned)j < 1024u) sc[sidx(m, j)] += cc[r];
      }
    }
  }
  __syncthreads();

  // Phase 3: softmax (max + exp/sum passes, vectorized f32x4; no normalize pass)
  {
    int row = tid >> 4, c0 = tid & 15;
    int rot = (row & 7) << 2;
    float* rb = sc + (row << 10);
    float mx = -1e30f;
#pragma unroll
    for (int t = 0; t < 16; t++) {
      int j0 = (c0 + (t << 4)) << 2;
      f32x4 v = *(const f32x4*)(rb + (j0 & ~31) + ((j0 + rot) & 31));
      mx = fmaxf(fmaxf(fmaxf(v[0], v[1]), fmaxf(v[2], v[3])), mx);
    }
    mx = fmaxf(mx, __shfl_xor(mx, 1));
    mx = fmaxf(mx, __shfl_xor(mx, 2));
    mx = fmaxf(mx, __shfl_xor(mx, 4));
    mx = fmaxf(mx, __shfl_xor(mx, 8));
    float sum = 0.f;
#pragma unroll
    for (int t = 0; t < 16; t++) {
      int j0 = (c0 + (t << 4)) << 2;
      float* p = rb + (j0 & ~31) + ((j0 + rot) & 31);
      f32x4 v = *(const f32x4*)p;
      v[0] = __expf(v[0] - mx); v[1] = __expf(v[1] - mx);
      v[2] = __expf(v[2] - mx); v[3] = __expf(v[3] - mx);
      sum += (v[0] + v[1]) + (v[2] + v[3]);
      *(f32x4*)p = v;
    }
    sum += __shfl_xor(sum, 1);
    sum += __shfl_xor(sum, 2);
    sum += __shfl_xor(sum, 4);
    sum += __shfl_xor(sum, 8);
    if (c0 == 0) rsArr[row] = 1.0f / sum;
  }
  __syncthreads();

  // Phase 4: PV — wave w computes O[0:16][w*16 : w*16+16]; scale by 1/sum here
  {
    f32x4 acc = {0.f, 0.f, 0.f, 0.f};
    const short* vp = vT + ((bh * 64 + w * 16 + c) << 10);
    const int m = c;
    const int rot = (m & 7) << 2;
    const float* rowbase = &sc[m << 10];
#pragma unroll 4
    for (int jt = 0; jt < 32; jt++) {
      int j0 = jt << 5;
      short8 bv = *(const short8*)(vp + j0 + q * 8);
      f32x4 pA = *(const f32x4*)(rowbase + j0 + ((q * 8 + rot) & 31));
      f32x4 pB = *(const f32x4*)(rowbase + j0 + ((q * 8 + 4 + rot) & 31));
      short8 pa;
      pa[0] = f2bf(pA[0]); pa[1] = f2bf(pA[1]); pa[2] = f2bf(pA[2]); pa[3] = f2bf(pA[3]);
      pa[4] = f2bf(pB[0]); pa[5] = f2bf(pB[1]); pa[6] = f2bf(pB[2]); pa[7] = f2bf(pB[3]);
      acc = MFMA16(pa, bv, acc);
    }
#pragma unroll
    for (int r = 0; r < 4; r++) {
      int row = q * 4 + r;
      ctx[((b * 1024 + i0 + row) << 9) + h * 64 + w * 16 + c] = f2bf(acc[r] * rsArr[row]);
    }
  }
}

// ---------------- launcher ----------------

extern "C" void kernel_launch(void* const* d_in, const int* in_sizes, int n_in,
                              void* d_out, int out_size, void* d_ws, size_t ws_size,
                              hipStream_t stream) {
  const float* query = (const float*)d_in[0];
  const float* key   = (const float*)d_in[1];
  const float* value = (const float*)d_in[2];
  const float* pos   = (const float*)d_in[3];
  const float* Wq    = (const float*)d_in[4];
  const float* Wk    = (const float*)d_in[5];
  const float* Wv    = (const float*)d_in[6];
  const float* Wp    = (const float*)d_in[7];
  const float* ub    = (const float*)d_in[8];
  const float* vb    = (const float*)d_in[9];
  const float* Wo    = (const float*)d_in[10];

  char* p = (char*)d_ws;
  auto alloc = [&](size_t bytes) {
    char* r = p;
    p += (bytes + 255) & ~(size_t)255;
    return r;
  };
  short* Xq  = (short*)alloc(8192 * 512 * 2);
  short* Xk  = (short*)alloc(8192 * 512 * 2);
  short* Xv  = (short*)alloc(8192 * 512 * 2);
  short* Xp  = (short*)alloc((size_t)16384 * 512 * 2);
  short* WtQ = (short*)alloc(512 * 512 * 2);
  short* WtK = (short*)alloc(512 * 512 * 2);
  short* WtV = (short*)alloc(512 * 512 * 2);
  short* WtP = (short*)alloc(512 * 512 * 2);
  short* WtO = (short*)alloc(512 * 512 * 2);
  short* quB = (short*)alloc((size_t)8 * 8 * 1024 * 64 * 2);
  short* qvB = (short*)alloc((size_t)8 * 8 * 1024 * 64 * 2);
  short* kbB = (short*)alloc((size_t)8 * 8 * 1024 * 64 * 2);
  short* vTB = (short*)alloc((size_t)8 * 8 * 1024 * 64 * 2);
  short* pbB = (short*)alloc((size_t)8 * 8 * 2048 * 64 * 2);
  short* ctxB = (short*)alloc((size_t)8 * 1024 * 512 * 2);

  cvt3<<<dim3(4096, 3), 256, 0, stream>>>(query, key, value, Xq, Xk, Xv);
  cvt_pos<<<8192, 256, 0, stream>>>(pos, Xp, 2097152);
  cvt_wt5<<<dim3(1024, 5), 256, 0, stream>>>(Wq, Wk, Wv, Wp, Wo, WtQ, WtK, WtV, WtP, WtO);

  proj2<0><<<dim3(64, 4), 256, 0, stream>>>(Xq, WtQ, ub, vb, quB, qvB, nullptr);
  proj2<1><<<dim3(64, 4), 256, 0, stream>>>(Xk, WtK, nullptr, nullptr, kbB, nullptr, nullptr);
  proj2<2><<<dim3(64, 4), 256, 0, stream>>>(Xv, WtV, nullptr, nullptr, vTB, nullptr, nullptr);
  proj2<3><<<dim3(128, 4), 256, 0, stream>>>(Xp, WtP, nullptr, nullptr, pbB, nullptr, nullptr);

  attn_kernel<<<4096, 256, 0, stream>>>(quB, qvB, kbB, vTB, pbB, ctxB);

  proj2<4><<<dim3(64, 4), 256, 0, stream>>>(ctxB, WtO, nullptr, nullptr, nullptr, nullptr,
                                            (float*)d_out);
}

// Round 4
// 391.616 us; speedup vs baseline: 1.7350x; 1.0645x over previous
//
#include <hip/hip_runtime.h>

typedef __attribute__((ext_vector_type(8))) short short8;
typedef __attribute__((ext_vector_type(4))) short short4_;
typedef __attribute__((ext_vector_type(4))) float f32x4;

#define MFMA16(a, b, c) __builtin_amdgcn_mfma_f32_16x16x32_bf16(a, b, c, 0, 0, 0)

__device__ __forceinline__ short f2bf(float f) {
  unsigned u = __float_as_uint(f);
  unsigned r = (u + 0x7FFFu + ((u >> 16) & 1u)) >> 16;  // RNE
  return (short)r;
}

__device__ __forceinline__ void glds16(const short* g, short* l) {
  __builtin_amdgcn_global_load_lds((const __attribute__((address_space(1))) unsigned int*)g,
                                   (__attribute__((address_space(3))) unsigned int*)l, 16, 0, 0);
}

// f32 score swizzle: rotate within 32-word blocks by 4*(m&7)
__device__ __forceinline__ int sidx(int m, int j) {
  return (m << 10) + (j & ~31) + ((j + ((m & 7) << 2)) & 31);
}
// bf16 P swizzle: rotate within 64-elem blocks by 8*(m&7)
__device__ __forceinline__ int bidx(int m, int j) {
  return (m << 10) + (j & ~63) + ((j + ((m & 7) << 3)) & 63);
}

// ---------------- converts ----------------

__global__ void cvt3(const float* __restrict__ s0, const float* __restrict__ s1,
                     const float* __restrict__ s2, short* __restrict__ d0,
                     short* __restrict__ d1, short* __restrict__ d2) {
  int i = blockIdx.x * 256 + threadIdx.x;
  const float* s = (blockIdx.y == 0) ? s0 : (blockIdx.y == 1) ? s1 : s2;
  short* d = (blockIdx.y == 0) ? d0 : (blockIdx.y == 1) ? d1 : d2;
  f32x4 v = ((const f32x4*)s)[i];
  short4_ o;
  o[0] = f2bf(v[0]); o[1] = f2bf(v[1]); o[2] = f2bf(v[2]); o[3] = f2bf(v[3]);
  ((short4_*)d)[i] = o;
}

__global__ void cvt_pos(const float* __restrict__ src, short* __restrict__ dst, int n4) {
  int i = blockIdx.x * 256 + threadIdx.x;
  if (i >= n4) return;
  int m = (i * 4) >> 9;
  short4_ o;
  if (m < 16376) {
    f32x4 v = ((const f32x4*)src)[i];
    o[0] = f2bf(v[0]); o[1] = f2bf(v[1]); o[2] = f2bf(v[2]); o[3] = f2bf(v[3]);
  } else {
    o[0] = 0; o[1] = 0; o[2] = 0; o[3] = 0;
  }
  ((short4_*)dst)[i] = o;
}

__global__ void cvt_wt5(const float* __restrict__ W0, const float* __restrict__ W1,
                        const float* __restrict__ W2, const float* __restrict__ W3,
                        const float* __restrict__ W4, short* __restrict__ T0,
                        short* __restrict__ T1, short* __restrict__ T2,
                        short* __restrict__ T3, short* __restrict__ T4) {
  int id = blockIdx.x * 256 + threadIdx.x;
  int n = id & 511, k = id >> 9;
  const float* W = (blockIdx.y == 0) ? W0 : (blockIdx.y == 1) ? W1
                 : (blockIdx.y == 2) ? W2 : (blockIdx.y == 3) ? W3 : W4;
  short* T = (blockIdx.y == 0) ? T0 : (blockIdx.y == 1) ? T1
           : (blockIdx.y == 2) ? T2 : (blockIdx.y == 3) ? T3 : T4;
  T[n * 512 + k] = f2bf(W[k * 512 + n]);
}

// ---------------- fused input projections (q,k,v,p) ----------------
// 128x128 tile, BK=32, global_load_lds staging. One launch, 1280 WGs.
__global__ __launch_bounds__(256, 3) void proj_in(
    const short* __restrict__ Xq, const short* __restrict__ Xk,
    const short* __restrict__ Xv, const short* __restrict__ Xp,
    const short* __restrict__ WtQ, const short* __restrict__ WtK,
    const short* __restrict__ WtV, const short* __restrict__ WtP,
    const float* __restrict__ biasU, const float* __restrict__ biasV,
    short* __restrict__ quB, short* __restrict__ qvB, short* __restrict__ kbB,
    short* __restrict__ vTB, short* __restrict__ pbB) {
  __shared__ short smem[8192];  // staging: As=[0,4096), Bs=[4096,8192); MODE2 reuses all 16KB
  short* As = smem;
  short* Bs = smem + 4096;

  const int tid = threadIdx.x;
  const int w = tid >> 6, l = tid & 63, q = l >> 4, c = l & 15;
  const int wm = (w & 1) << 6, wn = (w >> 1) << 6;

  int id = blockIdx.x;
  int mode, bx, by;
  const short *A, *Bt;
  if (id < 512) {           // p (largest) first
    mode = 3; bx = id & 127; by = id >> 7; A = Xp; Bt = WtP;
  } else if (id < 768) {
    mode = 0; id -= 512; bx = id & 63; by = id >> 6; A = Xq; Bt = WtQ;
  } else if (id < 1024) {
    mode = 1; id -= 768; bx = id & 63; by = id >> 6; A = Xk; Bt = WtK;
  } else {
    mode = 2; id -= 1024; bx = id & 63; by = id >> 6; A = Xv; Bt = WtV;
  }
  const int m0 = bx * 128, n0 = by * 128;

  f32x4 acc[4][4] = {};

  for (int kk = 0; kk < 512; kk += 32) {
#pragma unroll
    for (int i = 0; i < 2; i++) {
      int ci = i * 256 + tid;
      glds16(A + (m0 + (ci >> 2)) * 512 + kk + ((ci & 3) << 3), As + ci * 8);
      glds16(Bt + (n0 + (ci >> 2)) * 512 + kk + ((ci & 3) << 3), Bs + ci * 8);
    }
    __syncthreads();
    short8 af[4], bf[4];
#pragma unroll
    for (int i = 0; i < 4; i++) {
      af[i] = *(const short8*)(As + (wm + i * 16 + c) * 32 + q * 8);
      bf[i] = *(const short8*)(Bs + (wn + i * 16 + c) * 32 + q * 8);
    }
#pragma unroll
    for (int i = 0; i < 4; i++)
#pragma unroll
      for (int j = 0; j < 4; j++) acc[i][j] = MFMA16(af[i], bf[j], acc[i][j]);
    __syncthreads();
  }

  if (mode == 2) {
    // v: transpose 128x128 C through smem -> [B,H,Dh,S]
    const int bq = m0 >> 10;
#pragma unroll
    for (int ch = 0; ch < 2; ch++) {
      __syncthreads();
      if ((w & 1) == ch) {
#pragma unroll
        for (int i = 0; i < 4; i++)
#pragma unroll
          for (int j = 0; j < 4; j++)
#pragma unroll
            for (int r = 0; r < 4; r++)
              smem[(i * 16 + q * 4 + r) * 128 + wn + j * 16 + c] = f2bf(acc[i][j][r]);
      }
      __syncthreads();
      int d = tid >> 1, s0 = (tid & 1) << 5;
      int n = n0 + d, hh = n >> 6, dd = n & 63;
      int sbase = (m0 & 1023) + ch * 64 + s0;
      short* op = vTB + (((bq * 8 + hh) * 64 + dd) << 10) + sbase;
#pragma unroll
      for (int k2 = 0; k2 < 4; k2++) {
        short8 pk;
#pragma unroll
        for (int e = 0; e < 8; e++) pk[e] = smem[(s0 + k2 * 8 + e) * 128 + d];
        *(short8*)(op + (k2 << 3)) = pk;
      }
    }
    return;
  }

#pragma unroll
  for (int i = 0; i < 4; i++)
#pragma unroll
    for (int j = 0; j < 4; j++) {
      int n = n0 + wn + j * 16 + c;
      float bu = 0.f, bv = 0.f;
      if (mode == 0) { bu = biasU[n]; bv = biasV[n]; }
#pragma unroll
      for (int r = 0; r < 4; r++) {
        int mg = m0 + wm + i * 16 + q * 4 + r;
        float v = acc[i][j][r];
        if (mode == 0) {
          int b = mg >> 10, s = mg & 1023, h = n >> 6, d = n & 63;
          int idx = (((b * 8 + h) * 1024 + s) << 6) + d;
          quB[idx] = f2bf((v + bu) * 0.125f);
          qvB[idx] = f2bf((v + bv) * 0.125f);
        } else if (mode == 1) {
          int b = mg >> 10, s = mg & 1023, h = n >> 6, d = n & 63;
          kbB[(((b * 8 + h) * 1024 + s) << 6) + d] = f2bf(v);
        } else {
          if (mg < 16376) {
            int b = mg / 2047, rr = mg - b * 2047;
            int h = n >> 6, d = n & 63;
            pbB[(((b * 8 + h) * 2048 + rr) << 6) + d] = f2bf(v);
          }
        }
      }
    }
}

// ---------------- output projection: 64x128 tile ----------------
__global__ __launch_bounds__(256, 3) void proj_out(
    const short* __restrict__ A, const short* __restrict__ Bt, float* __restrict__ C) {
  __shared__ short smem[2048 + 4096];  // As=[64][32], Bs=[128][32]
  short* As = smem;
  short* Bs = smem + 2048;

  const int tid = threadIdx.x;
  const int w = tid >> 6, l = tid & 63, q = l >> 4, c = l & 15;
  const int m0 = blockIdx.x * 64, n0 = blockIdx.y * 128;

  f32x4 acc[4][2] = {};

  for (int kk = 0; kk < 512; kk += 32) {
#pragma unroll
    for (int i = 0; i < 2; i++) {
      int ci = i * 256 + tid;
      glds16(Bt + (n0 + (ci >> 2)) * 512 + kk + ((ci & 3) << 3), Bs + ci * 8);
    }
    glds16(A + (m0 + (tid >> 2)) * 512 + kk + ((tid & 3) << 3), As + tid * 8);
    __syncthreads();
    short8 af[4], bf[2];
#pragma unroll
    for (int i = 0; i < 4; i++) af[i] = *(const short8*)(As + (i * 16 + c) * 32 + q * 8);
#pragma unroll
    for (int j = 0; j < 2; j++)
      bf[j] = *(const short8*)(Bs + (w * 32 + j * 16 + c) * 32 + q * 8);
#pragma unroll
    for (int i = 0; i < 4; i++)
#pragma unroll
      for (int j = 0; j < 2; j++) acc[i][j] = MFMA16(af[i], bf[j], acc[i][j]);
    __syncthreads();
  }

#pragma unroll
  for (int i = 0; i < 4; i++)
#pragma unroll
    for (int j = 0; j < 2; j++) {
      int n = n0 + w * 32 + j * 16 + c;
#pragma unroll
      for (int r = 0; r < 4; r++) {
        int mg = m0 + i * 16 + q * 4 + r;
        C[mg * 512 + n] = acc[i][j][r];
      }
    }
}

// ---------------- fused attention ----------------
// 512 threads (8 waves), one WG per (b,h,16 q-rows). 64KB LDS -> 2 WG/CU, 16 waves/CU.
__global__ __launch_bounds__(512, 4) void attn_kernel(
    const short* __restrict__ qu, const short* __restrict__ qv,
    const short* __restrict__ kb, const short* __restrict__ vT,
    const short* __restrict__ pb, short* __restrict__ ctx) {
  __shared__ float sc[16 * 1024];
  __shared__ __align__(16) float rsArr[16];
  short* scb = (short*)sc;  // bf16 P overlay, [16][1024] bf16 = first 32KB

  const int tid = threadIdx.x;
  const int w = tid >> 6, l = tid & 63, q = l >> 4, c = l & 15;
  const int bh = blockIdx.x & 63;
  const int i0 = (blockIdx.x >> 6) << 4;
  const int b = bh >> 3, h = bh & 7;

  // Phase 1: content scores — 64 column tiles over 8 waves x 8 iters
  {
    const short* qp = qu + (((bh << 10) + i0 + c) << 6) + q * 8;
    short8 a0 = *(const short8*)(qp);
    short8 a1 = *(const short8*)(qp + 32);
    const short* kpb = kb + (((bh << 10) + c) << 6) + q * 8;
#pragma unroll 4
    for (int t = 0; t < 8; t++) {
      int j0 = (t * 8 + w) << 4;
      const short* kp = kpb + (j0 << 6);
      short8 b0 = *(const short8*)(kp);
      short8 b1 = *(const short8*)(kp + 32);
      f32x4 cc = {0.f, 0.f, 0.f, 0.f};
      cc = MFMA16(a0, b0, cc);
      cc = MFMA16(a1, b1, cc);
#pragma unroll
      for (int r = 0; r < 4; r++) sc[sidx(q * 4 + r, j0 + c)] = cc[r];
    }
  }
  // Phase 2: pos band (RMW scatter; rt disjoint across waves)
  {
    const short* qp = qv + (((bh << 10) + i0 + c) << 6) + q * 8;
    short8 a0 = *(const short8*)(qp);
    short8 a1 = *(const short8*)(qp + 32);
    __syncthreads();
    const short* ppb = pb + (((bh << 11) + c) << 6) + q * 8;
    const int r_lo = 1008 - i0;
#pragma unroll 4
    for (int t = 0; t < 8; t++) {
      int rt = w + t * 8;
      int r0 = r_lo + (rt << 4);
      const short* pp = ppb + (r0 << 6);
      short8 b0 = *(const short8*)(pp);
      short8 b1 = *(const short8*)(pp + 32);
      f32x4 cc = {0.f, 0.f, 0.f, 0.f};
      cc = MFMA16(a0, b0, cc);
      cc = MFMA16(a1, b1, cc);
#pragma unroll
      for (int r = 0; r < 4; r++) {
        int m = q * 4 + r;
        int j = rt * 16 - 15 + c + m;
        if ((unsigned)j < 1024u) sc[sidx(m, j)] += cc[r];
      }
    }
    if (w == 0) {  // tail rt = 64
      int r0 = r_lo + 1024;
      const short* pp = ppb + (r0 << 6);
      short8 b0 = *(const short8*)(pp);
      short8 b1 = *(const short8*)(pp + 32);
      f32x4 cc = {0.f, 0.f, 0.f, 0.f};
      cc = MFMA16(a0, b0, cc);
      cc = MFMA16(a1, b1, cc);
#pragma unroll
      for (int r = 0; r < 4; r++) {
        int m = q * 4 + r;
        int j = 1024 - 15 + c + m;
        if ((unsigned)j < 1024u) sc[sidx(m, j)] += cc[r];
      }
    }
  }
  __syncthreads();

  // Phase 3: softmax; exp in registers, P written back as bf16 (32KB overlay)
  {
    const int row = tid >> 5, c0 = tid & 31;
    const int rot = (row & 7) << 2;
    float* rb = sc + (row << 10);
    f32x4 v[8];
    float mx = -1e30f;
#pragma unroll
    for (int t = 0; t < 8; t++) {
      int j0 = (c0 + (t << 5)) << 2;
      v[t] = *(const f32x4*)(rb + (j0 & ~31) + ((j0 + rot) & 31));
      mx = fmaxf(fmaxf(fmaxf(v[t][0], v[t][1]), fmaxf(v[t][2], v[t][3])), mx);
    }
    mx = fmaxf(mx, __shfl_xor(mx, 1));
    mx = fmaxf(mx, __shfl_xor(mx, 2));
    mx = fmaxf(mx, __shfl_xor(mx, 4));
    mx = fmaxf(mx, __shfl_xor(mx, 8));
    mx = fmaxf(mx, __shfl_xor(mx, 16));
    __syncthreads();  // all f32 reads done before bf16 overlay writes
    float sum = 0.f;
#pragma unroll
    for (int t = 0; t < 8; t++) {
      int j0 = (c0 << 2) + (t << 7);
      f32x4 e;
      e[0] = __expf(v[t][0] - mx); e[1] = __expf(v[t][1] - mx);
      e[2] = __expf(v[t][2] - mx); e[3] = __expf(v[t][3] - mx);
      sum += (e[0] + e[1]) + (e[2] + e[3]);
      short4_ o;
      o[0] = f2bf(e[0]); o[1] = f2bf(e[1]); o[2] = f2bf(e[2]); o[3] = f2bf(e[3]);
      *(short4_*)(scb + bidx(row, j0)) = o;
    }
    sum += __shfl_xor(sum, 1);
    sum += __shfl_xor(sum, 2);
    sum += __shfl_xor(sum, 4);
    sum += __shfl_xor(sum, 8);
    sum += __shfl_xor(sum, 16);
    if (c0 == 0) rsArr[row] = 1.0f / sum;
  }
  __syncthreads();

  // Phase 4: PV. Wave-half 0: keys 0..511, half 1: keys 512..1023; combine via LDS.
  {
    const int half = w >> 2, wc = w & 3;
    f32x4 acc = {0.f, 0.f, 0.f, 0.f};
    const short* vp = vT + (((bh << 6) + wc * 16 + c) << 10) + (half << 9) + q * 8;
    const int rot8 = (c & 7) << 3;
    const short* prow = scb + (c << 10) + (half << 9);
#pragma unroll 4
    for (int jt = 0; jt < 16; jt++) {
      int jj = jt << 5;
      short8 bv = *(const short8*)(vp + jj);
      short8 pa = *(const short8*)(prow + (jj & ~63) + ((jj + q * 8 + rot8) & 63));
      acc = MFMA16(pa, bv, acc);
    }
    if (half == 1)
      *(f32x4*)(sc + 8192 + ((wc * 16 + c) << 4) + (q << 2)) = acc;
    __syncthreads();
    if (half == 0) {
      f32x4 part = *(const f32x4*)(sc + 8192 + ((wc * 16 + c) << 4) + (q << 2));
      f32x4 rsv = *(const f32x4*)&rsArr[q << 2];
#pragma unroll
      for (int r = 0; r < 4; r++) {
        int row = q * 4 + r;
        float o = (acc[r] + part[r]) * rsv[r];
        ctx[((b * 1024 + i0 + row) << 9) + h * 64 + wc * 16 + c] = f2bf(o);
      }
    }
  }
}

// ---------------- launcher ----------------

extern "C" void kernel_launch(void* const* d_in, const int* in_sizes, int n_in,
                              void* d_out, int out_size, void* d_ws, size_t ws_size,
                              hipStream_t stream) {
  const float* query = (const float*)d_in[0];
  const float* key   = (const float*)d_in[1];
  const float* value = (const float*)d_in[2];
  const float* pos   = (const float*)d_in[3];
  const float* Wq    = (const float*)d_in[4];
  const float* Wk    = (const float*)d_in[5];
  const float* Wv    = (const float*)d_in[6];
  const float* Wp    = (const float*)d_in[7];
  const float* ub    = (const float*)d_in[8];
  const float* vb    = (const float*)d_in[9];
  const float* Wo    = (const float*)d_in[10];

  char* p = (char*)d_ws;
  auto alloc = [&](size_t bytes) {
    char* r = p;
    p += (bytes + 255) & ~(size_t)255;
    return r;
  };
  short* Xq  = (short*)alloc(8192 * 512 * 2);
  short* Xk  = (short*)alloc(8192 * 512 * 2);
  short* Xv  = (short*)alloc(8192 * 512 * 2);
  short* Xp  = (short*)alloc((size_t)16384 * 512 * 2);
  short* WtQ = (short*)alloc(512 * 512 * 2);
  short* WtK = (short*)alloc(512 * 512 * 2);
  short* WtV = (short*)alloc(512 * 512 * 2);
  short* WtP = (short*)alloc(512 * 512 * 2);
  short* WtO = (short*)alloc(512 * 512 * 2);
  short* quB = (short*)alloc((size_t)8 * 8 * 1024 * 64 * 2);
  short* qvB = (short*)alloc((size_t)8 * 8 * 1024 * 64 * 2);
  short* kbB = (short*)alloc((size_t)8 * 8 * 1024 * 64 * 2);
  short* vTB = (short*)alloc((size_t)8 * 8 * 1024 * 64 * 2);
  short* pbB = (short*)alloc((size_t)8 * 8 * 2048 * 64 * 2);
  short* ctxB = (short*)alloc((size_t)8 * 1024 * 512 * 2);

  cvt3<<<dim3(4096, 3), 256, 0, stream>>>(query, key, value, Xq, Xk, Xv);
  cvt_pos<<<8192, 256, 0, stream>>>(pos, Xp, 2097152);
  cvt_wt5<<<dim3(1024, 5), 256, 0, stream>>>(Wq, Wk, Wv, Wp, Wo, WtQ, WtK, WtV, WtP, WtO);

  proj_in<<<1280, 256, 0, stream>>>(Xq, Xk, Xv, Xp, WtQ, WtK, WtV, WtP, ub, vb,
                                    quB, qvB, kbB, vTB, pbB);

  attn_kernel<<<4096, 512, 0, stream>>>(quB, qvB, kbB, vTB, pbB, ctxB);

  proj_out<<<dim3(128, 4), 256, 0, stream>>>(ctxB, WtO, (float*)d_out);
}

// Round 5
// 344.103 us; speedup vs baseline: 1.9745x; 1.1381x over previous
//
#include <hip/hip_runtime.h>

typedef __attribute__((ext_vector_type(8))) short short8;
typedef __attribute__((ext_vector_type(4))) short short4_;
typedef __attribute__((ext_vector_type(4))) float f32x4;

#define MFMA16(a, b, c) __builtin_amdgcn_mfma_f32_16x16x32_bf16(a, b, c, 0, 0, 0)

__device__ __forceinline__ short f2bf(float f) {
  unsigned u = __float_as_uint(f);
  unsigned r = (u + 0x7FFFu + ((u >> 16) & 1u)) >> 16;  // RNE
  return (short)r;
}

__device__ __forceinline__ void glds16(const short* g, short* l) {
  __builtin_amdgcn_global_load_lds((const __attribute__((address_space(1))) unsigned int*)g,
                                   (__attribute__((address_space(3))) unsigned int*)l, 16, 0, 0);
}

// f32 score swizzle: rotate within 32-word blocks by 4*(m&7)
__device__ __forceinline__ int sidx(int m, int j) {
  return (m << 10) + (j & ~31) + ((j + ((m & 7) << 2)) & 31);
}
// bf16 P swizzle: rotate within 64-elem blocks by 8*(m&7)
__device__ __forceinline__ int bidx(int m, int j) {
  return (m << 10) + (j & ~63) + ((j + ((m & 7) << 3)) & 63);
}

// ---------------- fused converts (q,k,v,pos,5 weights in one launch) ----------------
__global__ void cvt_all(const float* __restrict__ q, const float* __restrict__ k,
                        const float* __restrict__ v, const float* __restrict__ pos,
                        const float* __restrict__ W0, const float* __restrict__ W1,
                        const float* __restrict__ W2, const float* __restrict__ W3,
                        const float* __restrict__ W4, short* __restrict__ Xq,
                        short* __restrict__ Xk, short* __restrict__ Xv,
                        short* __restrict__ Xp, short* __restrict__ T0,
                        short* __restrict__ T1, short* __restrict__ T2,
                        short* __restrict__ T3, short* __restrict__ T4) {
  int id = blockIdx.x;
  int tid = threadIdx.x;
  if (id < 12288) {  // q/k/v: 3 x 4096 blocks, one f32x4 per thread
    int which = id >> 12;
    int i = (id & 4095) * 256 + tid;
    const float* s = (which == 0) ? q : (which == 1) ? k : v;
    short* d = (which == 0) ? Xq : (which == 1) ? Xk : Xv;
    f32x4 x = ((const f32x4*)s)[i];
    short4_ o;
    o[0] = f2bf(x[0]); o[1] = f2bf(x[1]); o[2] = f2bf(x[2]); o[3] = f2bf(x[3]);
    ((short4_*)d)[i] = o;
  } else if (id < 20480) {  // pos: 8192 blocks, pad rows 16376..16383 with 0
    int i = (id - 12288) * 256 + tid;
    int m = (i * 4) >> 9;
    short4_ o;
    if (m < 16376) {
      f32x4 x = ((const f32x4*)pos)[i];
      o[0] = f2bf(x[0]); o[1] = f2bf(x[1]); o[2] = f2bf(x[2]); o[3] = f2bf(x[3]);
    } else {
      o[0] = 0; o[1] = 0; o[2] = 0; o[3] = 0;
    }
    ((short4_*)Xp)[i] = o;
  } else {  // 5 weight transposes: Wt[n][k] = bf16(W[k][n])
    int t = id - 20480;
    int wsel = t >> 10;
    int i2 = (t & 1023) * 256 + tid;
    int n = i2 & 511, kk = i2 >> 9;
    const float* W = (wsel == 0) ? W0 : (wsel == 1) ? W1
                   : (wsel == 2) ? W2 : (wsel == 3) ? W3 : W4;
    short* T = (wsel == 0) ? T0 : (wsel == 1) ? T1
             : (wsel == 2) ? T2 : (wsel == 3) ? T3 : T4;
    T[n * 512 + kk] = f2bf(W[kk * 512 + n]);
  }
}

// ---------------- fused input projections (q,k,v,p) ----------------
// 128x128 tile, BK=32, global_load_lds staging. One launch, 1280 WGs.
__global__ __launch_bounds__(256, 3) void proj_in(
    const short* __restrict__ Xq, const short* __restrict__ Xk,
    const short* __restrict__ Xv, const short* __restrict__ Xp,
    const short* __restrict__ WtQ, const short* __restrict__ WtK,
    const short* __restrict__ WtV, const short* __restrict__ WtP,
    const float* __restrict__ biasU, const float* __restrict__ biasV,
    short* __restrict__ quB, short* __restrict__ qvB, short* __restrict__ kbB,
    short* __restrict__ vTB, short* __restrict__ pbB) {
  __shared__ short smem[8192];
  short* As = smem;
  short* Bs = smem + 4096;

  const int tid = threadIdx.x;
  const int w = tid >> 6, l = tid & 63, q = l >> 4, c = l & 15;
  const int wm = (w & 1) << 6, wn = (w >> 1) << 6;

  int id = blockIdx.x;
  int mode, bx, by;
  const short *A, *Bt;
  if (id < 512) {
    mode = 3; bx = id & 127; by = id >> 7; A = Xp; Bt = WtP;
  } else if (id < 768) {
    mode = 0; id -= 512; bx = id & 63; by = id >> 6; A = Xq; Bt = WtQ;
  } else if (id < 1024) {
    mode = 1; id -= 768; bx = id & 63; by = id >> 6; A = Xk; Bt = WtK;
  } else {
    mode = 2; id -= 1024; bx = id & 63; by = id >> 6; A = Xv; Bt = WtV;
  }
  const int m0 = bx * 128, n0 = by * 128;

  f32x4 acc[4][4] = {};

  for (int kk = 0; kk < 512; kk += 32) {
#pragma unroll
    for (int i = 0; i < 2; i++) {
      int ci = i * 256 + tid;
      glds16(A + (m0 + (ci >> 2)) * 512 + kk + ((ci & 3) << 3), As + ci * 8);
      glds16(Bt + (n0 + (ci >> 2)) * 512 + kk + ((ci & 3) << 3), Bs + ci * 8);
    }
    __syncthreads();
    short8 af[4], bf[4];
#pragma unroll
    for (int i = 0; i < 4; i++) {
      af[i] = *(const short8*)(As + (wm + i * 16 + c) * 32 + q * 8);
      bf[i] = *(const short8*)(Bs + (wn + i * 16 + c) * 32 + q * 8);
    }
#pragma unroll
    for (int i = 0; i < 4; i++)
#pragma unroll
      for (int j = 0; j < 4; j++) acc[i][j] = MFMA16(af[i], bf[j], acc[i][j]);
    __syncthreads();
  }

  if (mode == 2) {
    const int bq = m0 >> 10;
#pragma unroll
    for (int ch = 0; ch < 2; ch++) {
      __syncthreads();
      if ((w & 1) == ch) {
#pragma unroll
        for (int i = 0; i < 4; i++)
#pragma unroll
          for (int j = 0; j < 4; j++)
#pragma unroll
            for (int r = 0; r < 4; r++)
              smem[(i * 16 + q * 4 + r) * 128 + wn + j * 16 + c] = f2bf(acc[i][j][r]);
      }
      __syncthreads();
      int d = tid >> 1, s0 = (tid & 1) << 5;
      int n = n0 + d, hh = n >> 6, dd = n & 63;
      int sbase = (m0 & 1023) + ch * 64 + s0;
      short* op = vTB + (((bq * 8 + hh) * 64 + dd) << 10) + sbase;
#pragma unroll
      for (int k2 = 0; k2 < 4; k2++) {
        short8 pk;
#pragma unroll
        for (int e = 0; e < 8; e++) pk[e] = smem[(s0 + k2 * 8 + e) * 128 + d];
        *(short8*)(op + (k2 << 3)) = pk;
      }
    }
    return;
  }

#pragma unroll
  for (int i = 0; i < 4; i++)
#pragma unroll
    for (int j = 0; j < 4; j++) {
      int n = n0 + wn + j * 16 + c;
      float bu = 0.f, bv = 0.f;
      if (mode == 0) { bu = biasU[n]; bv = biasV[n]; }
#pragma unroll
      for (int r = 0; r < 4; r++) {
        int mg = m0 + wm + i * 16 + q * 4 + r;
        float v = acc[i][j][r];
        if (mode == 0) {
          int b = mg >> 10, s = mg & 1023, h = n >> 6, d = n & 63;
          int idx = (((b * 8 + h) * 1024 + s) << 6) + d;
          quB[idx] = f2bf((v + bu) * 0.125f);
          qvB[idx] = f2bf((v + bv) * 0.125f);
        } else if (mode == 1) {
          int b = mg >> 10, s = mg & 1023, h = n >> 6, d = n & 63;
          kbB[(((b * 8 + h) * 1024 + s) << 6) + d] = f2bf(v);
        } else {
          if (mg < 16376) {
            int b = mg / 2047, rr = mg - b * 2047;
            int h = n >> 6, d = n & 63;
            pbB[(((b * 8 + h) * 2048 + rr) << 6) + d] = f2bf(v);
          }
        }
      }
    }
}

// ---------------- output projection: 64x128 tile ----------------
__global__ __launch_bounds__(256, 3) void proj_out(
    const short* __restrict__ A, const short* __restrict__ Bt, float* __restrict__ C) {
  __shared__ short smem[2048 + 4096];
  short* As = smem;
  short* Bs = smem + 2048;

  const int tid = threadIdx.x;
  const int w = tid >> 6, l = tid & 63, q = l >> 4, c = l & 15;
  const int m0 = blockIdx.x * 64, n0 = blockIdx.y * 128;

  f32x4 acc[4][2] = {};

  for (int kk = 0; kk < 512; kk += 32) {
#pragma unroll
    for (int i = 0; i < 2; i++) {
      int ci = i * 256 + tid;
      glds16(Bt + (n0 + (ci >> 2)) * 512 + kk + ((ci & 3) << 3), Bs + ci * 8);
    }
    glds16(A + (m0 + (tid >> 2)) * 512 + kk + ((tid & 3) << 3), As + tid * 8);
    __syncthreads();
    short8 af[4], bf[2];
#pragma unroll
    for (int i = 0; i < 4; i++) af[i] = *(const short8*)(As + (i * 16 + c) * 32 + q * 8);
#pragma unroll
    for (int j = 0; j < 2; j++)
      bf[j] = *(const short8*)(Bs + (w * 32 + j * 16 + c) * 32 + q * 8);
#pragma unroll
    for (int i = 0; i < 4; i++)
#pragma unroll
      for (int j = 0; j < 2; j++) acc[i][j] = MFMA16(af[i], bf[j], acc[i][j]);
    __syncthreads();
  }

#pragma unroll
  for (int i = 0; i < 4; i++)
#pragma unroll
    for (int j = 0; j < 2; j++) {
      int n = n0 + w * 32 + j * 16 + c;
#pragma unroll
      for (int r = 0; r < 4; r++) {
        int mg = m0 + i * 16 + q * 4 + r;
        C[mg * 512 + n] = acc[i][j][r];
      }
    }
}

// ---------------- fused attention ----------------
// 1024 threads (16 waves), one WG per (b,h,32 q-rows). 128KB LDS -> 1 WG/CU.
// Every K/P fragment feeds 2 row-tiles (load:MFMA = 1:2).
__global__ __launch_bounds__(1024, 4) void attn_kernel(
    const short* __restrict__ qu, const short* __restrict__ qv,
    const short* __restrict__ kb, const short* __restrict__ vT,
    const short* __restrict__ pb, short* __restrict__ ctx) {
  __shared__ float sc[32 * 1024];       // 128KB scores
  __shared__ __align__(16) float rsArr[32];
  short* scb = (short*)sc;              // bf16 P overlay = first 64KB
  float* comb = sc + 16384;             // combine buffer (past overlay), 6KB used

  const int tid = threadIdx.x;
  const int w = tid >> 6, l = tid & 63, q = l >> 4, c = l & 15;
  const int bh = blockIdx.x & 63;
  const int i0 = (blockIdx.x >> 6) << 5;   // 32 q-rows per WG
  const int b = bh >> 3, h = bh & 7;

  // Phase 1: content scores — 64 col-tiles over 16 waves x 4 iters, 2 row-tiles each
  {
    const short* qp0 = qu + (((bh << 10) + i0 + c) << 6) + q * 8;
    short8 a00 = *(const short8*)(qp0);
    short8 a01 = *(const short8*)(qp0 + 32);
    short8 a10 = *(const short8*)(qp0 + 16 * 64);
    short8 a11 = *(const short8*)(qp0 + 16 * 64 + 32);
    const short* kpb = kb + (((bh << 10) + c) << 6) + q * 8;
#pragma unroll
    for (int t = 0; t < 4; t++) {
      int j0 = (t * 16 + w) << 4;
      const short* kp = kpb + (j0 << 6);
      short8 b0 = *(const short8*)(kp);
      short8 b1 = *(const short8*)(kp + 32);
      f32x4 cc0 = {0.f, 0.f, 0.f, 0.f}, cc1 = {0.f, 0.f, 0.f, 0.f};
      cc0 = MFMA16(a00, b0, cc0);
      cc0 = MFMA16(a01, b1, cc0);
      cc1 = MFMA16(a10, b0, cc1);
      cc1 = MFMA16(a11, b1, cc1);
#pragma unroll
      for (int r = 0; r < 4; r++) {
        sc[sidx(q * 4 + r, j0 + c)] = cc0[r];
        sc[sidx(16 + q * 4 + r, j0 + c)] = cc1[r];
      }
    }
  }
  // Phase 2: pos band, 66 r-tiles over 16 waves; scatter-add, 2 row-tiles each
  {
    const short* qp0 = qv + (((bh << 10) + i0 + c) << 6) + q * 8;
    short8 a00 = *(const short8*)(qp0);
    short8 a01 = *(const short8*)(qp0 + 32);
    short8 a10 = *(const short8*)(qp0 + 16 * 64);
    short8 a11 = *(const short8*)(qp0 + 16 * 64 + 32);
    __syncthreads();  // phase-1 writes visible before RMW
    const short* ppb = pb + (((bh << 11) + c) << 6) + q * 8;
    const int r_lo = 992 - i0;
#pragma unroll
    for (int t = 0; t < 5; t++) {
      int rt = w + 16 * t;
      if (rt < 66) {
        int r0 = r_lo + (rt << 4);
        const short* pp = ppb + (r0 << 6);
        short8 b0 = *(const short8*)(pp);
        short8 b1 = *(const short8*)(pp + 32);
        f32x4 cc0 = {0.f, 0.f, 0.f, 0.f}, cc1 = {0.f, 0.f, 0.f, 0.f};
        cc0 = MFMA16(a00, b0, cc0);
        cc0 = MFMA16(a01, b1, cc0);
        cc1 = MFMA16(a10, b0, cc1);
        cc1 = MFMA16(a11, b1, cc1);
#pragma unroll
        for (int r = 0; r < 4; r++) {
          int m = q * 4 + r;
          int j = r0 + c - 1023 + i0 + m;
          if ((unsigned)j < 1024u) sc[sidx(m, j)] += cc0[r];
          int j1 = j + 16;
          if ((unsigned)j1 < 1024u) sc[sidx(m + 16, j1)] += cc1[r];
        }
      }
    }
  }
  __syncthreads();

  // Phase 3: softmax; exp in registers, P written back as bf16 overlay
  {
    const int row = tid >> 5, c0 = tid & 31;
    const int rot = (row & 7) << 2;
    float* rb = sc + (row << 10);
    f32x4 v[8];
    float mx = -1e30f;
#pragma unroll
    for (int t = 0; t < 8; t++) {
      int j0 = (c0 + (t << 5)) << 2;
      v[t] = *(const f32x4*)(rb + (j0 & ~31) + ((j0 + rot) & 31));
      mx = fmaxf(fmaxf(fmaxf(v[t][0], v[t][1]), fmaxf(v[t][2], v[t][3])), mx);
    }
    mx = fmaxf(mx, __shfl_xor(mx, 1));
    mx = fmaxf(mx, __shfl_xor(mx, 2));
    mx = fmaxf(mx, __shfl_xor(mx, 4));
    mx = fmaxf(mx, __shfl_xor(mx, 8));
    mx = fmaxf(mx, __shfl_xor(mx, 16));
    __syncthreads();  // all f32 reads done before bf16 overlay writes
    float sum = 0.f;
#pragma unroll
    for (int t = 0; t < 8; t++) {
      int j0 = (c0 << 2) + (t << 7);
      f32x4 e;
      e[0] = __expf(v[t][0] - mx); e[1] = __expf(v[t][1] - mx);
      e[2] = __expf(v[t][2] - mx); e[3] = __expf(v[t][3] - mx);
      sum += (e[0] + e[1]) + (e[2] + e[3]);
      short4_ o;
      o[0] = f2bf(e[0]); o[1] = f2bf(e[1]); o[2] = f2bf(e[2]); o[3] = f2bf(e[3]);
      *(short4_*)(scb + bidx(row, j0)) = o;
    }
    sum += __shfl_xor(sum, 1);
    sum += __shfl_xor(sum, 2);
    sum += __shfl_xor(sum, 4);
    sum += __shfl_xor(sum, 8);
    sum += __shfl_xor(sum, 16);
    if (c0 == 0) rsArr[row] = 1.0f / sum;
  }
  __syncthreads();

  // Phase 4: PV. wave = (qt, wc): key quarter qt, col-tile wc; both row-tiles.
  {
    const int qt = w >> 2, wc = w & 3;
    f32x4 acc0 = {0.f, 0.f, 0.f, 0.f}, acc1 = {0.f, 0.f, 0.f, 0.f};
    const short* vp = vT + (((bh << 6) + wc * 16 + c) << 10) + (qt << 8) + q * 8;
    const int rot8 = (c & 7) << 3;
    const short* prow0 = scb + (c << 10) + (qt << 8);
    const short* prow1 = prow0 + (16 << 10);
#pragma unroll 4
    for (int jt = 0; jt < 8; jt++) {
      int jj = jt << 5;
      short8 bv = *(const short8*)(vp + jj);
      int off = (jj & ~63) + ((jj + q * 8 + rot8) & 63);  // qt*256 multiple of 64
      short8 pa0 = *(const short8*)(prow0 + off);
      short8 pa1 = *(const short8*)(prow1 + off);
      acc0 = MFMA16(pa0, bv, acc0);
      acc1 = MFMA16(pa1, bv, acc1);
    }
    if (qt > 0) {
      float* cb = comb + (((qt - 1) * 8 + wc) << 8) + (l << 2);
      *(f32x4*)cb = acc0;
      *(f32x4*)(cb + (4 << 8)) = acc1;
    }
    __syncthreads();
    if (qt == 0) {
#pragma unroll
      for (int p3 = 0; p3 < 3; p3++) {
        const float* cb = comb + ((p3 * 8 + wc) << 8) + (l << 2);
        f32x4 p0 = *(const f32x4*)cb;
        f32x4 p1 = *(const f32x4*)(cb + (4 << 8));
#pragma unroll
        for (int r = 0; r < 4; r++) { acc0[r] += p0[r]; acc1[r] += p1[r]; }
      }
#pragma unroll
      for (int r = 0; r < 4; r++) {
        int m = q * 4 + r;
        float o0 = acc0[r] * rsArr[m];
        float o1 = acc1[r] * rsArr[m + 16];
        ctx[((b * 1024 + i0 + m) << 9) + h * 64 + wc * 16 + c] = f2bf(o0);
        ctx[((b * 1024 + i0 + 16 + m) << 9) + h * 64 + wc * 16 + c] = f2bf(o1);
      }
    }
  }
}

// ---------------- launcher ----------------

extern "C" void kernel_launch(void* const* d_in, const int* in_sizes, int n_in,
                              void* d_out, int out_size, void* d_ws, size_t ws_size,
                              hipStream_t stream) {
  const float* query = (const float*)d_in[0];
  const float* key   = (const float*)d_in[1];
  const float* value = (const float*)d_in[2];
  const float* pos   = (const float*)d_in[3];
  const float* Wq    = (const float*)d_in[4];
  const float* Wk    = (const float*)d_in[5];
  const float* Wv    = (const float*)d_in[6];
  const float* Wp    = (const float*)d_in[7];
  const float* ub    = (const float*)d_in[8];
  const float* vb    = (const float*)d_in[9];
  const float* Wo    = (const float*)d_in[10];

  char* p = (char*)d_ws;
  auto alloc = [&](size_t bytes) {
    char* r = p;
    p += (bytes + 255) & ~(size_t)255;
    return r;
  };
  short* Xq  = (short*)alloc(8192 * 512 * 2);
  short* Xk  = (short*)alloc(8192 * 512 * 2);
  short* Xv  = (short*)alloc(8192 * 512 * 2);
  short* Xp  = (short*)alloc((size_t)16384 * 512 * 2);
  short* WtQ = (short*)alloc(512 * 512 * 2);
  short* WtK = (short*)alloc(512 * 512 * 2);
  short* WtV = (short*)alloc(512 * 512 * 2);
  short* WtP = (short*)alloc(512 * 512 * 2);
  short* WtO = (short*)alloc(512 * 512 * 2);
  short* quB = (short*)alloc((size_t)8 * 8 * 1024 * 64 * 2);
  short* qvB = (short*)alloc((size_t)8 * 8 * 1024 * 64 * 2);
  short* kbB = (short*)alloc((size_t)8 * 8 * 1024 * 64 * 2);
  short* vTB = (short*)alloc((size_t)8 * 8 * 1024 * 64 * 2);
  short* pbB = (short*)alloc((size_t)8 * 8 * 2048 * 64 * 2);
  short* ctxB = (short*)alloc((size_t)8 * 1024 * 512 * 2);

  cvt_all<<<25600, 256, 0, stream>>>(query, key, value, pos, Wq, Wk, Wv, Wp, Wo,
                                     Xq, Xk, Xv, Xp, WtQ, WtK, WtV, WtP, WtO);

  proj_in<<<1280, 256, 0, stream>>>(Xq, Xk, Xv, Xp, WtQ, WtK, WtV, WtP, ub, vb,
                                    quB, qvB, kbB, vTB, pbB);

  attn_kernel<<<2048, 1024, 0, stream>>>(quB, qvB, kbB, vTB, pbB, ctxB);

  proj_out<<<dim3(128, 4), 256, 0, stream>>>(ctxB, WtO, (float*)d_out);
}